// Round 2
// baseline (1580.670 us; speedup 1.0000x reference)
//
#include <hip/hip_runtime.h>

// Diagnostic round: full fp32 VALU implementation (no MFMA, no bf16) to
// validate all plumbing/semantics. prep also writes bf16 weights for the
// MFMA rounds that follow.

#define MUL 128
#define DIM 512
#define KTOT 640
#define INV_LIN 0.08838834764831845f   // 1/sqrt(128)
#define INV_TP  0.04419417382415922f   // 1/sqrt(512)

typedef float f32x4 __attribute__((ext_vector_type(4)));
typedef float f32x2 __attribute__((ext_vector_type(2)));

__device__ inline unsigned short f2bf(float x) {
    unsigned u = __float_as_uint(x);
    u += 0x7fffu + ((u >> 16) & 1u);
    return (unsigned short)(u >> 16);
}

// ---------------------------------------------------------------------------
// Prep: combined weights.  Wf[k][w] fp32 (used this round), Bt[w][k] bf16
// (for future MFMA rounds).  k<128: W_lin[k][w]*INV_LIN ; k>=128,kk=k-128,
// u=kk>>2,v=kk&3: W_tp[u][v][w]*INV_TP.
// ---------------------------------------------------------------------------
__global__ __launch_bounds__(256) void prep_weights(
        const float* __restrict__ Wl0, const float* __restrict__ Wl1,
        const float* __restrict__ Wt0, const float* __restrict__ Wt1,
        unsigned short* __restrict__ Bt0, unsigned short* __restrict__ Bt1,
        float* __restrict__ Wf0, float* __restrict__ Wf1) {
    int idx = blockIdx.x * 256 + threadIdx.x;
    if (idx >= 2 * MUL * KTOT) return;
    int mat = idx / (MUL * KTOT);
    int r   = idx % (MUL * KTOT);
    int w = r / KTOT, k = r % KTOT;
    const float* Wl = mat ? Wl1 : Wl0;
    const float* Wt = mat ? Wt1 : Wt0;
    float val;
    if (k < MUL) {
        val = Wl[k * MUL + w] * INV_LIN;
    } else {
        int kk = k - MUL;
        val = Wt[(kk >> 2) * 512 + (kk & 3) * 128 + w] * INV_TP;
    }
    (mat ? Bt1 : Bt0)[w * KTOT + k] = f2bf(val);
    (mat ? Wf1 : Wf0)[k * MUL + w] = val;
}

// ---------------------------------------------------------------------------
// out0 (cols 0..127), fp32.  Block = 128 threads: wq = tid&31 -> 4 consecutive
// w; ng = tid>>5 -> 2 nodes.  8 nodes/block.  A read straight from global
// (L1-cached; all 32 wq-threads share rows); W streamed from L2.
// ---------------------------------------------------------------------------
__global__ __launch_bounds__(128) void v0_fp32(
        const float* __restrict__ m_i, const float* __restrict__ nf,
        const float* __restrict__ attrs, const float* __restrict__ Wf0,
        float* __restrict__ out, int N) {
    int tid = threadIdx.x;
    int wq = tid & 31, ng = tid >> 5;
    long nb = (long)blockIdx.x * 8 + ng * 2;
    long n0 = nb < N ? nb : (N - 1);
    long n1 = (nb + 1) < N ? (nb + 1) : (N - 1);

    f32x4 at0 = *(const f32x4*)&attrs[n0 * 4];
    f32x4 at1 = *(const f32x4*)&attrs[n1 * 4];
    f32x4 acc0 = {0.f, 0.f, 0.f, 0.f}, acc1 = acc0;

    const float* A0 = &m_i[n0 * DIM];
    const float* A1 = &m_i[n1 * DIM];
    for (int k4 = 0; k4 < 32; ++k4) {           // lin: k = 0..127 (= u)
        f32x4 a0 = *(const f32x4*)&A0[k4 * 4];
        f32x4 a1 = *(const f32x4*)&A1[k4 * 4];
        #pragma unroll
        for (int j = 0; j < 4; ++j) {
            f32x4 wv = *(const f32x4*)&Wf0[(k4 * 4 + j) * MUL + wq * 4];
            acc0 += a0[j] * wv;
            acc1 += a1[j] * wv;
        }
    }
    const float* F0 = &nf[n0 * DIM];
    const float* F1 = &nf[n1 * DIM];
    for (int u = 0; u < 128; ++u) {             // tp: k = 128 + u*4 + v
        float f0 = F0[u], f1 = F1[u];
        #pragma unroll
        for (int v = 0; v < 4; ++v) {
            f32x4 wv = *(const f32x4*)&Wf0[(MUL + u * 4 + v) * MUL + wq * 4];
            acc0 += (f0 * at0[v]) * wv;
            acc1 += (f1 * at1[v]) * wv;
        }
    }
    if (nb < N)     *(f32x4*)&out[nb * DIM + wq * 4] = acc0;
    if (nb + 1 < N) *(f32x4*)&out[(nb + 1) * DIM + wq * 4] = acc1;
}

// ---------------------------------------------------------------------------
// out1 (cols 128..511), fp32.  4 nodes/block, 128 threads = 2 waves.
// Extended A built in LDS: A1q[node][m][k-quad] fp32, k<128 from m1
// (de-interleaved), k>=128 = f1[u][m]*attr[v].  Thread = w-pair p (w=2p,2p+1),
// wave nh -> node pair.  LDS reads are pure wave-broadcast.
// ---------------------------------------------------------------------------
__global__ __launch_bounds__(128) void v1_fp32(
        const float* __restrict__ m_i, const float* __restrict__ nf,
        const float* __restrict__ attrs, const float* __restrict__ Wf1,
        float* __restrict__ out, int N) {
    __shared__ f32x4 A1q[4][3][160];   // [node][m][k quad]; 30KB

    int tid = threadIdx.x;
    long nb = (long)blockIdx.x * 4;

    // lin part: m1[node][u][m] = row[128 + u*3 + m]
    for (int e = tid; e < 4 * 96; e += 128) {
        int nl = e / 96, q = e % 96;
        long node = (nb + nl) < N ? (nb + nl) : (N - 1);
        f32x4 x = *(const f32x4*)&m_i[node * DIM + MUL + q * 4];
        #pragma unroll
        for (int j = 0; j < 4; ++j) {
            int cc = q * 4 + j;                      // cc = u*3 + m
            ((float*)&A1q[nl][cc % 3][0])[cc / 3] = x[j];
        }
    }
    // tp part: A[m][128 + u*4 + v] = f1[u][m] * attr[v]
    for (int e = tid; e < 4 * 96; e += 128) {
        int nl = e / 96, q = e % 96;
        long node = (nb + nl) < N ? (nb + nl) : (N - 1);
        f32x4 y  = *(const f32x4*)&nf[node * DIM + MUL + q * 4];
        f32x4 at = *(const f32x4*)&attrs[node * 4];
        #pragma unroll
        for (int j = 0; j < 4; ++j) {
            int cc = q * 4 + j;
            A1q[nl][cc % 3][32 + cc / 3] = y[j] * at;
        }
    }
    __syncthreads();

    int p = tid & 63, nh = tid >> 6;    // w = 2p, 2p+1 ; nodes nh*2 + {0,1}
    f32x2 acc[2][3] = {};
    for (int k4 = 0; k4 < 160; ++k4) {
        f32x4 a[2][3];
        #pragma unroll
        for (int n = 0; n < 2; ++n)
            #pragma unroll
            for (int m = 0; m < 3; ++m)
                a[n][m] = A1q[nh * 2 + n][m][k4];
        #pragma unroll
        for (int j = 0; j < 4; ++j) {
            f32x2 wv = *(const f32x2*)&Wf1[(k4 * 4 + j) * MUL + p * 2];
            #pragma unroll
            for (int n = 0; n < 2; ++n)
                #pragma unroll
                for (int m = 0; m < 3; ++m)
                    acc[n][m] += a[n][m][j] * wv;
        }
    }

    #pragma unroll
    for (int n = 0; n < 2; ++n) {
        long node = nb + nh * 2 + n;
        if (node < N) {
            float* o = &out[node * DIM + MUL + p * 6];   // cols w*3+m, w=2p,2p+1
            f32x2 s0 = {acc[n][0][0], acc[n][1][0]};
            f32x2 s1 = {acc[n][2][0], acc[n][0][1]};
            f32x2 s2 = {acc[n][1][1], acc[n][2][1]};
            *(f32x2*)&o[0] = s0;
            *(f32x2*)&o[2] = s1;
            *(f32x2*)&o[4] = s2;
        }
    }
}

extern "C" void kernel_launch(void* const* d_in, const int* in_sizes, int n_in,
                              void* d_out, int out_size, void* d_ws, size_t ws_size,
                              hipStream_t stream) {
    const float* m_i  = (const float*)d_in[0];
    const float* nf   = (const float*)d_in[1];
    const float* attr = (const float*)d_in[2];
    const float* Wl0  = (const float*)d_in[3];
    const float* Wl1  = (const float*)d_in[4];
    const float* Wt0  = (const float*)d_in[5];
    const float* Wt1  = (const float*)d_in[6];
    float* out = (float*)d_out;
    int N = in_sizes[0] / DIM;

    unsigned short* Bt0 = (unsigned short*)d_ws;            // 160KB
    unsigned short* Bt1 = Bt0 + MUL * KTOT;                 // 160KB
    float* Wf0 = (float*)(Bt1 + MUL * KTOT);                // 320KB
    float* Wf1 = Wf0 + MUL * KTOT;                          // 320KB

    int prep_total = 2 * MUL * KTOT;
    hipLaunchKernelGGL(prep_weights, dim3((prep_total + 255) / 256), dim3(256), 0, stream,
                       Wl0, Wl1, Wt0, Wt1, Bt0, Bt1, Wf0, Wf1);
    hipLaunchKernelGGL(v0_fp32, dim3((N + 7) / 8), dim3(128), 0, stream,
                       m_i, nf, attr, Wf0, out, N);
    hipLaunchKernelGGL(v1_fp32, dim3((N + 3) / 4), dim3(128), 0, stream,
                       m_i, nf, attr, Wf1, out, N);
}

// Round 3
// 887.005 us; speedup vs baseline: 1.7820x; 1.7820x over previous
//
#include <hip/hip_runtime.h>

// Round 3: out0 stays fp32 (validated), out1 moves to bf16 MFMA 16x16x32.
// 1-bit experiment: isolates the MFMA machinery against a known-good baseline.

#define MUL 128
#define DIM 512
#define KTOT 640
#define NSTEPS 20
#define INV_LIN 0.08838834764831845f   // 1/sqrt(128)
#define INV_TP  0.04419417382415922f   // 1/sqrt(512)

typedef float f32x4 __attribute__((ext_vector_type(4)));
typedef float f32x2 __attribute__((ext_vector_type(2)));
typedef __bf16 bf16x8 __attribute__((ext_vector_type(8)));

__device__ inline unsigned short f2bf(float x) {
    unsigned u = __float_as_uint(x);
    u += 0x7fffu + ((u >> 16) & 1u);
    return (unsigned short)(u >> 16);
}

// ---------------------------------------------------------------------------
// Prep: combined weights.  Bt[w][k] bf16 (MFMA path), Wf[k][w] fp32 (VALU path).
// k<128: W_lin[k][w]*INV_LIN ; k>=128, kk=k-128, u=kk>>2, v=kk&3:
// W_tp[u][v][w]*INV_TP.   (value computation validated in round 2 via Wf)
// ---------------------------------------------------------------------------
__global__ __launch_bounds__(256) void prep_weights(
        const float* __restrict__ Wl0, const float* __restrict__ Wl1,
        const float* __restrict__ Wt0, const float* __restrict__ Wt1,
        unsigned short* __restrict__ Bt0, unsigned short* __restrict__ Bt1,
        float* __restrict__ Wf0, float* __restrict__ Wf1) {
    int idx = blockIdx.x * 256 + threadIdx.x;
    if (idx >= 2 * MUL * KTOT) return;
    int mat = idx / (MUL * KTOT);
    int r   = idx % (MUL * KTOT);
    int w = r / KTOT, k = r % KTOT;
    const float* Wl = mat ? Wl1 : Wl0;
    const float* Wt = mat ? Wt1 : Wt0;
    float val;
    if (k < MUL) {
        val = Wl[k * MUL + w] * INV_LIN;
    } else {
        int kk = k - MUL;
        val = Wt[(kk >> 2) * 512 + (kk & 3) * 128 + w] * INV_TP;
    }
    (mat ? Bt1 : Bt0)[w * KTOT + k] = f2bf(val);
    (mat ? Wf1 : Wf0)[k * MUL + w] = val;
}

// ---------------------------------------------------------------------------
// out0 (cols 0..127), fp32 VALU — unchanged from the validated round-2 kernel.
// ---------------------------------------------------------------------------
__global__ __launch_bounds__(128) void v0_fp32(
        const float* __restrict__ m_i, const float* __restrict__ nf,
        const float* __restrict__ attrs, const float* __restrict__ Wf0,
        float* __restrict__ out, int N) {
    int tid = threadIdx.x;
    int wq = tid & 31, ng = tid >> 5;
    long nb = (long)blockIdx.x * 8 + ng * 2;
    long n0 = nb < N ? nb : (N - 1);
    long n1 = (nb + 1) < N ? (nb + 1) : (N - 1);

    f32x4 at0 = *(const f32x4*)&attrs[n0 * 4];
    f32x4 at1 = *(const f32x4*)&attrs[n1 * 4];
    f32x4 acc0 = {0.f, 0.f, 0.f, 0.f}, acc1 = acc0;

    const float* A0 = &m_i[n0 * DIM];
    const float* A1 = &m_i[n1 * DIM];
    for (int k4 = 0; k4 < 32; ++k4) {
        f32x4 a0 = *(const f32x4*)&A0[k4 * 4];
        f32x4 a1 = *(const f32x4*)&A1[k4 * 4];
        #pragma unroll
        for (int j = 0; j < 4; ++j) {
            f32x4 wv = *(const f32x4*)&Wf0[(k4 * 4 + j) * MUL + wq * 4];
            acc0 += a0[j] * wv;
            acc1 += a1[j] * wv;
        }
    }
    const float* F0 = &nf[n0 * DIM];
    const float* F1 = &nf[n1 * DIM];
    for (int u = 0; u < 128; ++u) {
        float f0 = F0[u], f1 = F1[u];
        #pragma unroll
        for (int v = 0; v < 4; ++v) {
            f32x4 wv = *(const f32x4*)&Wf0[(MUL + u * 4 + v) * MUL + wq * 4];
            acc0 += (f0 * at0[v]) * wv;
            acc1 += (f1 * at1[v]) * wv;
        }
    }
    if (nb < N)     *(f32x4*)&out[nb * DIM + wq * 4] = acc0;
    if (nb + 1 < N) *(f32x4*)&out[(nb + 1) * DIM + wq * 4] = acc1;
}

// ---------------------------------------------------------------------------
// out1 (cols 128..511), bf16 MFMA.  32 nodes/block, 6 waves = m(0..2) x half.
// Per wave: 16 nodes x 128 w-cols, K=640 in 20 steps of 32.
// A: row=lane&15 (node), k-slot=(lane>>4)*8+i.  B: col=lane&15 (w), same k-slot.
// D: col=lane&15 (w), row=(lane>>4)*4+r (node).
// M1/F1: de-interleaved components in LDS bf16 [3][32][136] (272B stride).
// Output staged via LDS (fp32) for coalesced float4 dump.
// ---------------------------------------------------------------------------
#define K1_POOL 62464
__global__ __launch_bounds__(384) void k_out1(
        const float* __restrict__ m_i, const float* __restrict__ nf,
        const float* __restrict__ attrs, const unsigned short* __restrict__ Bt1,
        float* __restrict__ out, int N) {
    __shared__ __align__(16) char pool[K1_POOL];
    __bf16 (*Blds)[40]    = (__bf16(*)[40])(pool);                 // [128][40]
    __bf16 (*M1)[32][136] = (__bf16(*)[32][136])(pool + 10240);
    __bf16 (*F1)[32][136] = (__bf16(*)[32][136])(pool + 36352);

    int tid = threadIdx.x;
    int wv = tid >> 6, l = tid & 63;
    int lr = l & 15, g = l >> 4;
    int m = wv >> 1, half = wv & 1;

    long nodeBase = (long)blockIdx.x * 32;

    // stage m1/f1 de-interleaved: 32 nodes x 96 float4 chunks each
    for (int c = tid; c < 3072; c += 384) {
        int nl = c / 96, q = c % 96;
        long node = (nodeBase + nl) < N ? (nodeBase + nl) : (N - 1);
        f32x4 x = *(const f32x4*)&m_i[node * DIM + MUL + q * 4];
        f32x4 y = *(const f32x4*)&nf [node * DIM + MUL + q * 4];
        #pragma unroll
        for (int j = 0; j < 4; ++j) {
            int cc = q * 4 + j;                      // cc = u*3 + m
            M1[cc % 3][nl][cc / 3] = (__bf16)x[j];
            F1[cc % 3][nl][cc / 3] = (__bf16)y[j];
        }
    }

    long nodeA = nodeBase + half * 16 + lr;
    if (nodeA >= N) nodeA = N - 1;
    f32x4 at = *(const f32x4*)&attrs[nodeA * 4];

    f32x4 acc[8] = {};

    for (int ks = 0; ks < NSTEPS; ++ks) {
        __syncthreads();                 // ks=0: also covers M1/F1 staging
        for (int c = tid; c < 512; c += 384) {
            int row = c >> 2, cg = c & 3;      // row = w, 32 cols of k
            *(f32x4*)&Blds[row][cg * 8] =
                *(const f32x4*)&Bt1[row * KTOT + ks * 32 + cg * 8];
        }
        __syncthreads();

        bf16x8 af;
        int nl = half * 16 + lr;
        if (ks < 4) {                    // lin: k = u, from de-interleaved m1
            af = *(const bf16x8*)&M1[m][nl][ks * 32 + g * 8];
        } else {                         // tp: k = 128 + u*4 + v = f1[u]*attr[v]
            int u0 = (ks - 4) * 8 + g * 2;
            float fx = (float)F1[m][nl][u0];
            float fy = (float)F1[m][nl][u0 + 1];
            af[0]=(__bf16)(fx*at[0]); af[1]=(__bf16)(fx*at[1]);
            af[2]=(__bf16)(fx*at[2]); af[3]=(__bf16)(fx*at[3]);
            af[4]=(__bf16)(fy*at[0]); af[5]=(__bf16)(fy*at[1]);
            af[6]=(__bf16)(fy*at[2]); af[7]=(__bf16)(fy*at[3]);
        }

        #pragma unroll
        for (int nt = 0; nt < 8; ++nt) {
            bf16x8 bf = *(const bf16x8*)&Blds[nt * 16 + lr][g * 8];
            acc[nt] = __builtin_amdgcn_mfma_f32_16x16x32_bf16(af, bf, acc[nt], 0, 0, 0);
        }
    }

    // epilogue: acc -> LDS fp32 (reuse pool) -> coalesced float4 dump
    __syncthreads();
    float* Ost = (float*)pool;           // [32][384]
    int nlD = half * 16 + g * 4;
    #pragma unroll
    for (int nt = 0; nt < 8; ++nt)
        #pragma unroll
        for (int r = 0; r < 4; ++r)
            Ost[(nlD + r) * 384 + (nt * 16 + lr) * 3 + m] = acc[nt][r];
    __syncthreads();
    for (int c = tid; c < 3072; c += 384) {
        int nl = c / 96, q = c % 96;
        long node = nodeBase + nl;
        if (node < N)
            *(f32x4*)&out[node * DIM + MUL + q * 4] =
                *(const f32x4*)&Ost[nl * 384 + q * 4];
    }
}

extern "C" void kernel_launch(void* const* d_in, const int* in_sizes, int n_in,
                              void* d_out, int out_size, void* d_ws, size_t ws_size,
                              hipStream_t stream) {
    const float* m_i  = (const float*)d_in[0];
    const float* nf   = (const float*)d_in[1];
    const float* attr = (const float*)d_in[2];
    const float* Wl0  = (const float*)d_in[3];
    const float* Wl1  = (const float*)d_in[4];
    const float* Wt0  = (const float*)d_in[5];
    const float* Wt1  = (const float*)d_in[6];
    float* out = (float*)d_out;
    int N = in_sizes[0] / DIM;

    unsigned short* Bt0 = (unsigned short*)d_ws;            // 160KB
    unsigned short* Bt1 = Bt0 + MUL * KTOT;                 // 160KB
    float* Wf0 = (float*)(Bt1 + MUL * KTOT);                // 320KB
    float* Wf1 = Wf0 + MUL * KTOT;                          // 320KB

    int prep_total = 2 * MUL * KTOT;
    hipLaunchKernelGGL(prep_weights, dim3((prep_total + 255) / 256), dim3(256), 0, stream,
                       Wl0, Wl1, Wt0, Wt1, Bt0, Bt1, Wf0, Wf1);
    hipLaunchKernelGGL(v0_fp32, dim3((N + 7) / 8), dim3(128), 0, stream,
                       m_i, nf, attr, Wf0, out, N);
    hipLaunchKernelGGL(k_out1, dim3((N + 31) / 32), dim3(384), 0, stream,
                       m_i, nf, attr, Bt1, out, N);
}

// Round 6
// 394.632 us; speedup vs baseline: 4.0054x; 2.2477x over previous
//
#include <hip/hip_runtime.h>

// Round 6: no templates. k_out1 = VERBATIM round-3 passing text.
// k_out0 = same text with the component axis m repurposed as node-group axis
// mg (96 nodes/block), so both kernels are mechanically congruent:
// 384 threads, 6 waves, identical LDS layout and per-wave instruction stream.

#define MUL 128
#define DIM 512
#define KTOT 640
#define NSTEPS 20
#define INV_LIN 0.08838834764831845f   // 1/sqrt(128)
#define INV_TP  0.04419417382415922f   // 1/sqrt(512)

typedef float f32x4 __attribute__((ext_vector_type(4)));
typedef __bf16 bf16x8 __attribute__((ext_vector_type(8)));

__device__ inline unsigned short f2bf(float x) {
    unsigned u = __float_as_uint(x);
    u += 0x7fffu + ((u >> 16) & 1u);
    return (unsigned short)(u >> 16);
}

// ---------------------------------------------------------------------------
// Prep: combined transposed weights Bt[w][k] bf16, scales folded (validated r2;
// write-index validated via Bt1/k_out1 r3).
// ---------------------------------------------------------------------------
__global__ __launch_bounds__(256) void prep_weights(
        const float* __restrict__ Wl0, const float* __restrict__ Wl1,
        const float* __restrict__ Wt0, const float* __restrict__ Wt1,
        unsigned short* __restrict__ Bt0, unsigned short* __restrict__ Bt1) {
    int idx = blockIdx.x * 256 + threadIdx.x;
    if (idx >= 2 * MUL * KTOT) return;
    int mat = idx / (MUL * KTOT);
    int r   = idx % (MUL * KTOT);
    int w = r / KTOT, k = r % KTOT;
    const float* Wl = mat ? Wl1 : Wl0;
    const float* Wt = mat ? Wt1 : Wt0;
    float val;
    if (k < MUL) {
        val = Wl[k * MUL + w] * INV_LIN;
    } else {
        int kk = k - MUL;
        val = Wt[(kk >> 2) * 512 + (kk & 3) * 128 + w] * INV_TP;
    }
    (mat ? Bt1 : Bt0)[w * KTOT + k] = f2bf(val);
}

// ---------------------------------------------------------------------------
// out0 (cols 0..127).  96 nodes/block, 6 waves = mg(0..2 node-group) x half.
// Mechanically congruent to k_out1: same thread count, LDS layout, loop
// shapes, per-wave instruction sequence.  mg indexes node groups (32 each)
// instead of xyz components.
// ---------------------------------------------------------------------------
#define K_POOL 62464
__global__ __launch_bounds__(384) void k_out0(
        const float* __restrict__ m_i, const float* __restrict__ nf,
        const float* __restrict__ attrs, const unsigned short* __restrict__ Bt0,
        float* __restrict__ out, int N) {
    __shared__ __align__(16) char pool[K_POOL];
    __bf16 (*Blds)[40]    = (__bf16(*)[40])(pool);
    __bf16 (*M0)[32][136] = (__bf16(*)[32][136])(pool + 10240);
    __bf16 (*F0)[32][136] = (__bf16(*)[32][136])(pool + 36352);

    int tid = threadIdx.x;
    int wv = tid >> 6, l = tid & 63;
    int lr = l & 15, g = l >> 4;
    int mg = wv >> 1, half = wv & 1;          // mg = node-group (was m)

    long nodeBase = (long)blockIdx.x * 96;

    // stage 96 nodes x cols 0..127: M0[group][node-in-group][u]
    for (int c = tid; c < 3072; c += 384) {
        int nl96 = c / 32, q = c % 32;
        long node = (nodeBase + nl96) < N ? (nodeBase + nl96) : (N - 1);
        f32x4 x = *(const f32x4*)&m_i[node * DIM + q * 4];
        f32x4 y = *(const f32x4*)&nf [node * DIM + q * 4];
        int mgs = nl96 >> 5, nls = nl96 & 31;
        #pragma unroll
        for (int j = 0; j < 4; ++j) {
            M0[mgs][nls][q * 4 + j] = (__bf16)x[j];
            F0[mgs][nls][q * 4 + j] = (__bf16)y[j];
        }
    }

    long nodeA = nodeBase + mg * 32 + half * 16 + lr;
    if (nodeA >= N) nodeA = N - 1;
    f32x4 at = *(const f32x4*)&attrs[nodeA * 4];

    f32x4 acc[8] = {};

    for (int ks = 0; ks < NSTEPS; ++ks) {
        __syncthreads();                 // ks=0: also covers M0/F0 staging
        for (int c = tid; c < 512; c += 384) {
            int row = c >> 2, cg = c & 3;
            *(f32x4*)&Blds[row][cg * 8] =
                *(const f32x4*)&Bt0[row * KTOT + ks * 32 + cg * 8];
        }
        __syncthreads();

        bf16x8 af;
        int nl = half * 16 + lr;
        if (ks < 4) {                    // lin: k = u
            af = *(const bf16x8*)&M0[mg][nl][ks * 32 + g * 8];
        } else {                         // tp: k = 128 + u*4 + v = f[u]*attr[v]
            int u0 = (ks - 4) * 8 + g * 2;
            float fx = (float)F0[mg][nl][u0];
            float fy = (float)F0[mg][nl][u0 + 1];
            af[0]=(__bf16)(fx*at[0]); af[1]=(__bf16)(fx*at[1]);
            af[2]=(__bf16)(fx*at[2]); af[3]=(__bf16)(fx*at[3]);
            af[4]=(__bf16)(fy*at[0]); af[5]=(__bf16)(fy*at[1]);
            af[6]=(__bf16)(fy*at[2]); af[7]=(__bf16)(fy*at[3]);
        }

        #pragma unroll
        for (int nt = 0; nt < 8; ++nt) {
            bf16x8 bf = *(const bf16x8*)&Blds[nt * 16 + lr][g * 8];
            acc[nt] = __builtin_amdgcn_mfma_f32_16x16x32_bf16(af, bf, acc[nt], 0, 0, 0);
        }
    }

    // epilogue: acc -> LDS fp32 [96][128] -> coalesced float4 dump
    __syncthreads();
    float* Ost = (float*)pool;
    int nlD = mg * 32 + half * 16 + g * 4;
    #pragma unroll
    for (int nt = 0; nt < 8; ++nt)
        #pragma unroll
        for (int r = 0; r < 4; ++r)
            Ost[(nlD + r) * 128 + nt * 16 + lr] = acc[nt][r];
    __syncthreads();
    for (int c = tid; c < 3072; c += 384) {
        int nl96 = c / 32, q = c % 32;
        long node = nodeBase + nl96;
        if (node < N)
            *(f32x4*)&out[node * DIM + q * 4] =
                *(const f32x4*)&Ost[nl96 * 128 + q * 4];
    }
}

// ---------------------------------------------------------------------------
// out1 (cols 128..511) — VERBATIM round-3 passing kernel.
// ---------------------------------------------------------------------------
__global__ __launch_bounds__(384) void k_out1(
        const float* __restrict__ m_i, const float* __restrict__ nf,
        const float* __restrict__ attrs, const unsigned short* __restrict__ Bt1,
        float* __restrict__ out, int N) {
    __shared__ __align__(16) char pool[K_POOL];
    __bf16 (*Blds)[40]    = (__bf16(*)[40])(pool);
    __bf16 (*M1)[32][136] = (__bf16(*)[32][136])(pool + 10240);
    __bf16 (*F1)[32][136] = (__bf16(*)[32][136])(pool + 36352);

    int tid = threadIdx.x;
    int wv = tid >> 6, l = tid & 63;
    int lr = l & 15, g = l >> 4;
    int m = wv >> 1, half = wv & 1;

    long nodeBase = (long)blockIdx.x * 32;

    for (int c = tid; c < 3072; c += 384) {
        int nl = c / 96, q = c % 96;
        long node = (nodeBase + nl) < N ? (nodeBase + nl) : (N - 1);
        f32x4 x = *(const f32x4*)&m_i[node * DIM + MUL + q * 4];
        f32x4 y = *(const f32x4*)&nf [node * DIM + MUL + q * 4];
        #pragma unroll
        for (int j = 0; j < 4; ++j) {
            int cc = q * 4 + j;                      // cc = u*3 + m
            M1[cc % 3][nl][cc / 3] = (__bf16)x[j];
            F1[cc % 3][nl][cc / 3] = (__bf16)y[j];
        }
    }

    long nodeA = nodeBase + half * 16 + lr;
    if (nodeA >= N) nodeA = N - 1;
    f32x4 at = *(const f32x4*)&attrs[nodeA * 4];

    f32x4 acc[8] = {};

    for (int ks = 0; ks < NSTEPS; ++ks) {
        __syncthreads();
        for (int c = tid; c < 512; c += 384) {
            int row = c >> 2, cg = c & 3;
            *(f32x4*)&Blds[row][cg * 8] =
                *(const f32x4*)&Bt1[row * KTOT + ks * 32 + cg * 8];
        }
        __syncthreads();

        bf16x8 af;
        int nl = half * 16 + lr;
        if (ks < 4) {
            af = *(const bf16x8*)&M1[m][nl][ks * 32 + g * 8];
        } else {
            int u0 = (ks - 4) * 8 + g * 2;
            float fx = (float)F1[m][nl][u0];
            float fy = (float)F1[m][nl][u0 + 1];
            af[0]=(__bf16)(fx*at[0]); af[1]=(__bf16)(fx*at[1]);
            af[2]=(__bf16)(fx*at[2]); af[3]=(__bf16)(fx*at[3]);
            af[4]=(__bf16)(fy*at[0]); af[5]=(__bf16)(fy*at[1]);
            af[6]=(__bf16)(fy*at[2]); af[7]=(__bf16)(fy*at[3]);
        }

        #pragma unroll
        for (int nt = 0; nt < 8; ++nt) {
            bf16x8 bf = *(const bf16x8*)&Blds[nt * 16 + lr][g * 8];
            acc[nt] = __builtin_amdgcn_mfma_f32_16x16x32_bf16(af, bf, acc[nt], 0, 0, 0);
        }
    }

    __syncthreads();
    float* Ost = (float*)pool;
    int nlD = half * 16 + g * 4;
    #pragma unroll
    for (int nt = 0; nt < 8; ++nt)
        #pragma unroll
        for (int r = 0; r < 4; ++r)
            Ost[(nlD + r) * 384 + (nt * 16 + lr) * 3 + m] = acc[nt][r];
    __syncthreads();
    for (int c = tid; c < 3072; c += 384) {
        int nl = c / 96, q = c % 96;
        long node = nodeBase + nl;
        if (node < N)
            *(f32x4*)&out[node * DIM + MUL + q * 4] =
                *(const f32x4*)&Ost[nl * 384 + q * 4];
    }
}

extern "C" void kernel_launch(void* const* d_in, const int* in_sizes, int n_in,
                              void* d_out, int out_size, void* d_ws, size_t ws_size,
                              hipStream_t stream) {
    const float* m_i  = (const float*)d_in[0];
    const float* nf   = (const float*)d_in[1];
    const float* attr = (const float*)d_in[2];
    const float* Wl0  = (const float*)d_in[3];
    const float* Wl1  = (const float*)d_in[4];
    const float* Wt0  = (const float*)d_in[5];
    const float* Wt1  = (const float*)d_in[6];
    float* out = (float*)d_out;
    int N = in_sizes[0] / DIM;

    unsigned short* Bt0 = (unsigned short*)d_ws;
    unsigned short* Bt1 = Bt0 + MUL * KTOT;

    int prep_total = 2 * MUL * KTOT;
    hipLaunchKernelGGL(prep_weights, dim3((prep_total + 255) / 256), dim3(256), 0, stream,
                       Wl0, Wl1, Wt0, Wt1, Bt0, Bt1);
    hipLaunchKernelGGL(k_out0, dim3((N + 95) / 96), dim3(384), 0, stream,
                       m_i, nf, attr, Bt0, out, N);
    hipLaunchKernelGGL(k_out1, dim3((N + 31) / 32), dim3(384), 0, stream,
                       m_i, nf, attr, Bt1, out, N);
}